// Round 6
// baseline (241.588 us; speedup 1.0000x reference)
//
#include <hip/hip_runtime.h>
#include <math.h>

// Problem shape (fixed by the reference): x = (B=4, S=8192, D=1024) float32.
// out[b,s,d] = x[b,s,d] + pos[s,d]
//   pos[s,d] = sin(s / 10000^((d+1)/D)) if d even, cos(...) if d odd.
#define PE_S 8192
#define PE_D 1024
#define PE_B 4

#define PE_K 8                                  // quads per thread
#define PE_QTOTAL (PE_B * PE_S * PE_D / 4)      // 8,388,608 float4 quads
#define PE_NT (PE_QTOTAL / PE_K)                // 1,048,576 threads
#define PE_THREADS 256
#define PE_BLOCKS (PE_NT / PE_THREADS)          // 4096 blocks

typedef float f32x4 __attribute__((ext_vector_type(4)));

// Native-trig positional value (branch-free, single BB). v_sin/cos take
// REVOLUTIONS; wrev = 10000^-((j+1)/D) / (2pi) folds -log2(2pi) into one
// v_exp_f32. fmaf residual keeps the fract reduction effectively fp64;
// absmax has stayed 0.03125 across all rounds with this path.
__device__ __forceinline__ float pe_sin(float fs, float wrev) {
    float t = fs * wrev;
    float r = t - floorf(t);
    r += fmaf(fs, wrev, -t);            // exact product residual
    return __builtin_amdgcn_sinf(r);    // sin(2*pi*r)
}
__device__ __forceinline__ float pe_cos(float fs, float wrev) {
    float t = fs * wrev;
    float r = t - floorf(t);
    r += fmaf(fs, wrev, -t);
    return __builtin_amdgcn_cosf(r);    // cos(2*pi*r)
}

// 8-DEEP PINNED LOAD PIPELINE. Lesson of rounds 1/3/5: the machine scheduler
// ALWAYS re-sinks hoisted loads to just before their use (VGPR came back
// 24-32 every time), collapsing every software pipeline written in source
// order and serializing each wave to load->wait->store per 1 KiB. Fix:
// issue all 8 loads, then __builtin_amdgcn_sched_barrier(0) -- a hard fence
// nothing may cross -- then trig+stores. The waitcnt pass then emits COUNTED
// vmcnt(7..0) waits as each store consumes its load: 8 KiB in flight per
// wave, ~190 VALU trig ops filling the latency shadow. Second effect:
// 8 reads then 8 writes per wave coarsens the DRAM read/write interleave
// ~8x (fill = write-only = no mixing hits 6.7 TB/s; our mixed stream sat
// at 3.7). No nt anywhere: FETCH=67MB shows L3 serves half the x reads --
// keep that (r4's nt-loads forfeited it).
// Stride PE_NT is a multiple of 256 quads -> d0 constant per thread ->
// exp2f weights computed once; only s changes across the 8 chunks.
__global__ __launch_bounds__(PE_THREADS) void position_encoder_kernel(
    const float* __restrict__ x, float* __restrict__ out) {
    const int tid = blockIdx.x * blockDim.x + threadIdx.x;   // 0..PE_NT-1
    const int d0  = (tid & (PE_D / 4 - 1)) << 2;             // constant

    const float A2 = -0.012976281620653760f;  // -log2(10000)/1024
    const float C  = -2.6514961294723187f;    // -log2(2*pi)
    const float w0 = exp2f(fmaf((float)(d0 + 1), A2, C));
    const float w1 = exp2f(fmaf((float)(d0 + 2), A2, C));
    const float w2 = exp2f(fmaf((float)(d0 + 3), A2, C));
    const float w3 = exp2f(fmaf((float)(d0 + 4), A2, C));

    // ---- issue all 8 loads (coalesced streams, 16 MB apart) ----
    f32x4 v[PE_K];
#pragma unroll
    for (int k = 0; k < PE_K; ++k) {
        v[k] = *reinterpret_cast<const f32x4*>(
            x + (size_t)(tid + k * PE_NT) * 4);
    }

    // hard scheduling fence: loads may NOT be sunk below this point
    __builtin_amdgcn_sched_barrier(0);

    // ---- trig + add + store per chunk (counted vmcnt waits, 8-deep) ----
#pragma unroll
    for (int k = 0; k < PE_K; ++k) {
        const int q = tid + k * PE_NT;
        const int s = (q >> 8) & (PE_S - 1);
        const float fs = (float)s;

        f32x4 p;
        p.x = pe_sin(fs, w0);   // d0   even -> sin
        p.y = pe_cos(fs, w1);   // d0+1 odd  -> cos
        p.z = pe_sin(fs, w2);   // d0+2 even -> sin
        p.w = pe_cos(fs, w3);   // d0+3 odd  -> cos

        *reinterpret_cast<f32x4*>(out + (size_t)q * 4) = v[k] + p;
    }
}

extern "C" void kernel_launch(void* const* d_in, const int* in_sizes, int n_in,
                              void* d_out, int out_size, void* d_ws, size_t ws_size,
                              hipStream_t stream) {
    const float* x = (const float*)d_in[0];
    float* out = (float*)d_out;
    position_encoder_kernel<<<PE_BLOCKS, PE_THREADS, 0, stream>>>(x, out);
}